// Round 1
// baseline (98.828 us; speedup 1.0000x reference)
//
#include <hip/hip_runtime.h>
#include <hip/hip_bf16.h>
#include <stdint.h>

#define H_ 128
#define THREADS 256
#define EDGES_PER_BLOCK 128   // 4 waves x 32 edges

typedef __bf16 bf16x8 __attribute__((ext_vector_type(8)));
typedef float  f32x4  __attribute__((ext_vector_type(4)));

// ---------------------------------------------------------------------------
// Prep: convert W1 (fp32 [256][128] row-major) into bf16 MFMA B-fragment order.
// Element layout in wfrag: idx = ks*4096 + nt*512 + lane*8 + j  where
//   k = ks*32 + (lane>>4)*8 + j   (K index into [zu|za] concat, 0..255)
//   n = nt*16 + (lane&15)         (output channel, 0..127)
// ---------------------------------------------------------------------------
__global__ void prep_w1_kernel(const float* __restrict__ W1,
                               __bf16* __restrict__ wfrag) {
    int t  = blockIdx.x * 256 + threadIdx.x;   // 0..32767
    int j  = t & 7;
    int ln = (t >> 3) & 63;
    int nt = (t >> 9) & 7;
    int ks = (t >> 12) & 7;
    int k  = ks * 32 + ((ln >> 4) << 3) + j;
    int n  = nt * 16 + (ln & 15);
    wfrag[t] = (__bf16)W1[k * H_ + n];
}

__device__ inline bf16x8 pack8(float4 a, float4 b) {
    bf16x8 v;
    v[0] = (__bf16)a.x; v[1] = (__bf16)a.y; v[2] = (__bf16)a.z; v[3] = (__bf16)a.w;
    v[4] = (__bf16)b.x; v[5] = (__bf16)b.y; v[6] = (__bf16)b.z; v[7] = (__bf16)b.w;
    return v;
}

// Gather one edge's A fragments for this lane. zu/za already offset by g*8.
__device__ inline void gather_edge(const float* __restrict__ zu,
                                   const float* __restrict__ za,
                                   bf16x8* A) {
    #pragma unroll
    for (int ks = 0; ks < 4; ++ks) {
        float4 x = *(const float4*)(zu + ks * 32);
        float4 y = *(const float4*)(zu + ks * 32 + 4);
        A[ks] = pack8(x, y);
    }
    #pragma unroll
    for (int ks = 0; ks < 4; ++ks) {
        float4 x = *(const float4*)(za + ks * 32);
        float4 y = *(const float4*)(za + ks * 32 + 4);
        A[4 + ks] = pack8(x, y);
    }
}

__global__ __launch_bounds__(THREADS, 2)
void edge_decoder_kernel(const float* __restrict__ z_user,
                         const float* __restrict__ z_anime,
                         const int*   __restrict__ row,
                         const int*   __restrict__ col,
                         const float* __restrict__ W1,
                         const float* __restrict__ b1,
                         const float* __restrict__ W2,
                         const float* __restrict__ b2,
                         const __bf16* __restrict__ wfrag,
                         int use_ws,
                         float* __restrict__ out,
                         int E) {
    // B fragments: [ks][nt][lane] of 8 bf16 = 64 KiB
    __shared__ bf16x8 Bf[8][8][64];

    const int tid = threadIdx.x;

    if (use_ws) {
        // cooperative 16B copies, coalesced
        const int4* src = (const int4*)wfrag;
        int4*       dst = (int4*)&Bf[0][0][0];
        #pragma unroll
        for (int i = 0; i < 16; ++i)
            dst[tid + i * THREADS] = src[tid + i * THREADS];
    } else {
        // fallback: convert W1 in-block (coalesced fp32 read, scattered b16 write)
        __bf16* d = (__bf16*)&Bf[0][0][0];
        for (int idx = tid; idx < 2 * H_ * H_; idx += THREADS) {
            int k  = idx >> 7, n = idx & 127;
            int ks = k >> 5, g = (k >> 3) & 3, j = k & 7;
            int nt = n >> 4;
            int ln = (g << 4) | (n & 15);
            d[ks * 4096 + nt * 512 + ln * 8 + j] = (__bf16)W1[idx];
        }
    }
    __syncthreads();

    const int lane = tid & 63;
    const int wv   = tid >> 6;
    const int g    = lane >> 4;   // k-group for A/B operands
    const int m    = lane & 15;   // row-within-Mtile for A; channel-within-Ntile for C
    const int base = blockIdx.x * EDGES_PER_BLOCK + wv * 32;

    // ---- gather A for two 16-edge M-tiles (fp32 -> bf16 in registers) ----
    bf16x8 A0[8], A1[8];
    {
        int e0 = base + m;        int e0c = e0 < E ? e0 : 0;
        int e1 = base + 16 + m;   int e1c = e1 < E ? e1 : 0;
        int r0 = row[e0c], c0 = col[e0c];
        int r1 = row[e1c], c1 = col[e1c];
        gather_edge(z_user + (size_t)r0 * H_ + g * 8,
                    z_anime + (size_t)c0 * H_ + g * 8, A0);
        gather_edge(z_user + (size_t)r1 * H_ + g * 8,
                    z_anime + (size_t)c1 * H_ + g * 8, A1);
    }

    // ---- MFMA main: 8 N-tiles x 8 K-steps, B reused across both M-tiles ----
    f32x4 acc0[8], acc1[8];
    #pragma unroll
    for (int nt = 0; nt < 8; ++nt) {
        acc0[nt] = (f32x4){0.f, 0.f, 0.f, 0.f};
        acc1[nt] = (f32x4){0.f, 0.f, 0.f, 0.f};
    }
    #pragma unroll
    for (int nt = 0; nt < 8; ++nt) {
        #pragma unroll
        for (int ks = 0; ks < 8; ++ks) {
            bf16x8 b = Bf[ks][nt][lane];
            acc0[nt] = __builtin_amdgcn_mfma_f32_16x16x32_bf16(A0[ks], b, acc0[nt], 0, 0, 0);
            acc1[nt] = __builtin_amdgcn_mfma_f32_16x16x32_bf16(A1[ks], b, acc1[nt], 0, 0, 0);
        }
    }

    // ---- epilogue: h = relu(acc + b1); out = h @ W2 + b2 ----
    // C/D layout: channel = nt*16 + m, edge-within-tile = g*4 + reg
    float w2v[8], b1v[8];
    #pragma unroll
    for (int nt = 0; nt < 8; ++nt) {
        int ch = nt * 16 + m;
        w2v[nt] = W2[ch];
        b1v[nt] = b1[ch];
    }
    const float bb = b2[0];

    #pragma unroll
    for (int tile = 0; tile < 2; ++tile) {
        float ps[4];
        #pragma unroll
        for (int r = 0; r < 4; ++r) {
            float s = 0.f;
            #pragma unroll
            for (int nt = 0; nt < 8; ++nt) {
                f32x4 a = tile ? acc1[nt] : acc0[nt];
                float h = a[r] + b1v[nt];
                s = fmaf(fmaxf(h, 0.f), w2v[nt], s);
            }
            ps[r] = s;
        }
        // reduce over the 16 lanes holding the channel slices of each edge
        #pragma unroll
        for (int off = 1; off < 16; off <<= 1) {
            #pragma unroll
            for (int r = 0; r < 4; ++r)
                ps[r] += __shfl_xor(ps[r], off, 64);
        }
        if (m == 0) {
            int eb = base + tile * 16 + g * 4;
            if (eb < E) {
                float4 o = make_float4(ps[0] + bb, ps[1] + bb, ps[2] + bb, ps[3] + bb);
                *(float4*)(out + eb) = o;
            }
        }
    }
}

extern "C" void kernel_launch(void* const* d_in, const int* in_sizes, int n_in,
                              void* d_out, int out_size, void* d_ws, size_t ws_size,
                              hipStream_t stream) {
    const float* z_user  = (const float*)d_in[0];
    const float* z_anime = (const float*)d_in[1];
    const int*   row     = (const int*)d_in[2];
    const int*   col     = (const int*)d_in[3];
    const float* W1      = (const float*)d_in[4];
    const float* b1      = (const float*)d_in[5];
    const float* W2      = (const float*)d_in[6];
    const float* b2      = (const float*)d_in[7];
    float*       out     = (float*)d_out;
    const int E = in_sizes[2];

    int use_ws = (d_ws != nullptr && ws_size >= 2u * H_ * H_ * sizeof(__bf16)) ? 1 : 0;
    __bf16* wfrag = (__bf16*)d_ws;

    if (use_ws)
        prep_w1_kernel<<<128, 256, 0, stream>>>(W1, wfrag);

    int nb = (E + EDGES_PER_BLOCK - 1) / EDGES_PER_BLOCK;
    edge_decoder_kernel<<<nb, THREADS, 0, stream>>>(
        z_user, z_anime, row, col, W1, b1, W2, b2, wfrag, use_ws, out, E);
}

// Round 2
// 82.297 us; speedup vs baseline: 1.2009x; 1.2009x over previous
//
#include <hip/hip_runtime.h>
#include <hip/hip_bf16.h>
#include <stdint.h>

#define H_ 128
#define THREADS 256
#define EDGES_PER_BLOCK 128   // 4 waves x 32 edges

typedef __bf16 bf16x8 __attribute__((ext_vector_type(8)));
typedef float  f32x4  __attribute__((ext_vector_type(4)));

// ---------------------------------------------------------------------------
// wfrag layout (bf16 MFMA B-fragment order), idx = ks*4096 + nt*512 + lane*8 + j
//   k = ks*32 + (lane>>4)*8 + j   (K index into [zu|za] concat, 0..255)
//   n = nt*16 + (lane&15)         (output channel, 0..127)
// Phase p stages ks in [4p, 4p+4) = contiguous 32 KiB chunk.
// ---------------------------------------------------------------------------

__device__ inline bf16x8 pack8(float4 a, float4 b) {
    bf16x8 v;
    v[0] = (__bf16)a.x; v[1] = (__bf16)a.y; v[2] = (__bf16)a.z; v[3] = (__bf16)a.w;
    v[4] = (__bf16)b.x; v[5] = (__bf16)b.y; v[6] = (__bf16)b.z; v[7] = (__bf16)b.w;
    return v;
}

// Combined prep: W1 -> bf16 fragment order (first 128 blocks), z_anime -> bf16.
__global__ void prep_kernel(const float* __restrict__ W1,
                            const float* __restrict__ za,
                            __bf16* __restrict__ wfrag,
                            __bf16* __restrict__ za_bf,
                            int nza) {
    int t = blockIdx.x * 256 + threadIdx.x;
    if (t < 32768) {
        int j  = t & 7;
        int ln = (t >> 3) & 63;
        int nt = (t >> 9) & 7;
        int ks = (t >> 12) & 7;
        int k  = ks * 32 + ((ln >> 4) << 3) + j;
        int n  = nt * 16 + (ln & 15);
        wfrag[t] = (__bf16)W1[k * H_ + n];
    } else {
        long i = (long)(t - 32768) * 8;
        if (i < nza) {
            float4 a = *(const float4*)(za + i);
            float4 b = *(const float4*)(za + i + 4);
            *(bf16x8*)(za_bf + i) = pack8(a, b);
        }
    }
}

__global__ __launch_bounds__(THREADS, 3)
void edge_decoder_kernel(const float* __restrict__ z_user,
                         const float* __restrict__ z_anime,
                         const int*   __restrict__ row,
                         const int*   __restrict__ col,
                         const float* __restrict__ W1,
                         const float* __restrict__ b1,
                         const float* __restrict__ W2,
                         const float* __restrict__ b2,
                         const __bf16* __restrict__ wfrag,
                         const __bf16* __restrict__ za_bf,
                         int use_ws,
                         float* __restrict__ out,
                         int E) {
    // One K-phase of B fragments: [ks 0..3][nt][lane] of 8 bf16 = 32 KiB
    __shared__ bf16x8 Bf[4][8][64];

    const int tid  = threadIdx.x;
    const int lane = tid & 63;
    const int wv   = tid >> 6;
    const int g    = lane >> 4;   // k-group within 32-wide K-step
    const int m    = lane & 15;   // edge-within-Mtile (A); channel-within-Ntile (C)
    const int base = blockIdx.x * EDGES_PER_BLOCK + wv * 32;

    int e0 = base + m;        int e0c = e0 < E ? e0 : 0;
    int e1 = base + 16 + m;   int e1c = e1 < E ? e1 : 0;
    const int r0 = row[e0c], c0 = col[e0c];
    const int r1 = row[e1c], c1 = col[e1c];

    // ---- gather zu (fp32 -> bf16 in registers), phase-0 A operands ----
    bf16x8 Au0[4], Au1[4];
    {
        const float* zu0 = z_user + (size_t)r0 * H_ + g * 8;
        const float* zu1 = z_user + (size_t)r1 * H_ + g * 8;
        #pragma unroll
        for (int ks = 0; ks < 4; ++ks) {
            float4 x0 = *(const float4*)(zu0 + ks * 32);
            float4 y0 = *(const float4*)(zu0 + ks * 32 + 4);
            float4 x1 = *(const float4*)(zu1 + ks * 32);
            float4 y1 = *(const float4*)(zu1 + ks * 32 + 4);
            Au0[ks] = pack8(x0, y0);
            Au1[ks] = pack8(x1, y1);
        }
    }

    // ---- stage W1 phase 0 (ks 0..3) ----
    if (use_ws) {
        const int4* src = (const int4*)wfrag;       // phase 0 at offset 0
        int4*       dst = (int4*)&Bf[0][0][0];
        #pragma unroll
        for (int i = 0; i < 8; ++i)
            dst[tid + i * THREADS] = src[tid + i * THREADS];
    } else {
        __bf16* d = (__bf16*)&Bf[0][0][0];
        for (int idx = tid; idx < H_ * H_; idx += THREADS) {
            int k = idx >> 7, n = idx & 127;
            int ks = k >> 5, gg = (k >> 3) & 3, j = k & 7;
            int nt = n >> 4, ln = (gg << 4) | (n & 15);
            d[ks * 4096 + nt * 512 + ln * 8 + j] = (__bf16)W1[k * H_ + n];
        }
    }
    __syncthreads();

    f32x4 acc0[8], acc1[8];
    #pragma unroll
    for (int nt = 0; nt < 8; ++nt) {
        acc0[nt] = (f32x4){0.f, 0.f, 0.f, 0.f};
        acc1[nt] = (f32x4){0.f, 0.f, 0.f, 0.f};
    }

    // ---- phase 0 MFMAs: zu @ W1[:128] ----
    #pragma unroll
    for (int nt = 0; nt < 8; ++nt) {
        #pragma unroll
        for (int ks = 0; ks < 4; ++ks) {
            bf16x8 b = Bf[ks][nt][lane];
            acc0[nt] = __builtin_amdgcn_mfma_f32_16x16x32_bf16(Au0[ks], b, acc0[nt], 0, 0, 0);
            acc1[nt] = __builtin_amdgcn_mfma_f32_16x16x32_bf16(Au1[ks], b, acc1[nt], 0, 0, 0);
        }
    }

    // ---- issue za loads (overlap with barrier + phase-1 staging) ----
    bf16x8 Aa0[4], Aa1[4];
    if (use_ws) {
        const __bf16* za0 = za_bf + (size_t)c0 * H_ + g * 8;
        const __bf16* za1 = za_bf + (size_t)c1 * H_ + g * 8;
        #pragma unroll
        for (int ks = 0; ks < 4; ++ks) {
            Aa0[ks] = *(const bf16x8*)(za0 + ks * 32);
            Aa1[ks] = *(const bf16x8*)(za1 + ks * 32);
        }
    } else {
        const float* za0 = z_anime + (size_t)c0 * H_ + g * 8;
        const float* za1 = z_anime + (size_t)c1 * H_ + g * 8;
        #pragma unroll
        for (int ks = 0; ks < 4; ++ks) {
            float4 x0 = *(const float4*)(za0 + ks * 32);
            float4 y0 = *(const float4*)(za0 + ks * 32 + 4);
            float4 x1 = *(const float4*)(za1 + ks * 32);
            float4 y1 = *(const float4*)(za1 + ks * 32 + 4);
            Aa0[ks] = pack8(x0, y0);
            Aa1[ks] = pack8(x1, y1);
        }
    }

    __syncthreads();   // phase-0 Bf reads complete before overwrite

    // ---- stage W1 phase 1 (ks 4..7) ----
    if (use_ws) {
        const int4* src = (const int4*)wfrag + 2048;   // 32 KiB offset
        int4*       dst = (int4*)&Bf[0][0][0];
        #pragma unroll
        for (int i = 0; i < 8; ++i)
            dst[tid + i * THREADS] = src[tid + i * THREADS];
    } else {
        __bf16* d = (__bf16*)&Bf[0][0][0];
        for (int idx = tid; idx < H_ * H_; idx += THREADS) {
            int k = idx >> 7, n = idx & 127;
            int ks = k >> 5, gg = (k >> 3) & 3, j = k & 7;
            int nt = n >> 4, ln = (gg << 4) | (n & 15);
            d[ks * 4096 + nt * 512 + ln * 8 + j] = (__bf16)W1[(H_ + k) * H_ + n];
        }
    }
    __syncthreads();

    // ---- phase 1 MFMAs: za @ W1[128:] ----
    #pragma unroll
    for (int nt = 0; nt < 8; ++nt) {
        #pragma unroll
        for (int ks = 0; ks < 4; ++ks) {
            bf16x8 b = Bf[ks][nt][lane];
            acc0[nt] = __builtin_amdgcn_mfma_f32_16x16x32_bf16(Aa0[ks], b, acc0[nt], 0, 0, 0);
            acc1[nt] = __builtin_amdgcn_mfma_f32_16x16x32_bf16(Aa1[ks], b, acc1[nt], 0, 0, 0);
        }
    }

    // ---- epilogue: h = relu(acc + b1); out = h @ W2 + b2 ----
    // C/D layout: channel = nt*16 + m, edge-within-tile = g*4 + reg
    float w2v[8], b1v[8];
    #pragma unroll
    for (int nt = 0; nt < 8; ++nt) {
        int ch = nt * 16 + m;
        w2v[nt] = W2[ch];
        b1v[nt] = b1[ch];
    }
    const float bb = b2[0];

    #pragma unroll
    for (int tile = 0; tile < 2; ++tile) {
        float ps[4];
        #pragma unroll
        for (int r = 0; r < 4; ++r) {
            float s = 0.f;
            #pragma unroll
            for (int nt = 0; nt < 8; ++nt) {
                f32x4 a = tile ? acc1[nt] : acc0[nt];
                float h = a[r] + b1v[nt];
                s = fmaf(fmaxf(h, 0.f), w2v[nt], s);
            }
            ps[r] = s;
        }
        #pragma unroll
        for (int off = 1; off < 16; off <<= 1) {
            #pragma unroll
            for (int r = 0; r < 4; ++r)
                ps[r] += __shfl_xor(ps[r], off, 64);
        }
        if (m == 0) {
            int eb = base + tile * 16 + g * 4;
            if (eb < E) {
                float4 o = make_float4(ps[0] + bb, ps[1] + bb, ps[2] + bb, ps[3] + bb);
                *(float4*)(out + eb) = o;
            }
        }
    }
}

extern "C" void kernel_launch(void* const* d_in, const int* in_sizes, int n_in,
                              void* d_out, int out_size, void* d_ws, size_t ws_size,
                              hipStream_t stream) {
    const float* z_user  = (const float*)d_in[0];
    const float* z_anime = (const float*)d_in[1];
    const int*   row     = (const int*)d_in[2];
    const int*   col     = (const int*)d_in[3];
    const float* W1      = (const float*)d_in[4];
    const float* b1      = (const float*)d_in[5];
    const float* W2      = (const float*)d_in[6];
    const float* b2      = (const float*)d_in[7];
    float*       out     = (float*)d_out;
    const int E   = in_sizes[2];
    const int nza = in_sizes[1];

    const size_t wfrag_bytes = 2u * H_ * H_ * sizeof(__bf16);   // 64 KiB
    const size_t need = wfrag_bytes + (size_t)nza * sizeof(__bf16);
    int use_ws = (d_ws != nullptr && ws_size >= need) ? 1 : 0;

    __bf16* wfrag = (__bf16*)d_ws;
    __bf16* za_bf = (__bf16*)((char*)d_ws + wfrag_bytes);

    if (use_ws) {
        int za_threads = (nza + 7) / 8;
        int nb_prep = 128 + (za_threads + 255) / 256;
        prep_kernel<<<nb_prep, 256, 0, stream>>>(W1, z_anime, wfrag, za_bf, nza);
    }

    int nb = (E + EDGES_PER_BLOCK - 1) / EDGES_PER_BLOCK;
    edge_decoder_kernel<<<nb, THREADS, 0, stream>>>(
        z_user, z_anime, row, col, W1, b1, W2, b2, wfrag, za_bf, use_ws, out, E);
}